// Round 14
// baseline (368.310 us; speedup 1.0000x reference)
//
#include <hip/hip_runtime.h>

typedef __attribute__((ext_vector_type(8))) short short8;
typedef __attribute__((ext_vector_type(4))) float f32x4;

#define B_    8
#define CI    256
#define CO    256
#define Hh    160
#define Ww    160
#define HP    162
#define WP    162
#define HWp   (Hh * Ww)                 // 25600
#define XPAD_ELEMS (B_ * HP * WP * CI)  // 53,747,712 bf16
#define W3_ELEMS   (9 * CI * CO)        // 589,824 bf16 (granule order)
#define NT    36                        // 4 ci-chunks x 9 shifts, BK=64
#define BSLOT (160 * 64)                // shorts per B slot: 160px x 64ci = 20KB

// fused prep grid partition
#define NBORD 644
#define NPW   2304                      // 589824 / 256
#define NPX   (B_ * Hh * 4 * 3)        // 15360

__device__ __forceinline__ unsigned short f2bf(float f) {
  unsigned int u = __float_as_uint(f);
  u += 0x7FFFu + ((u >> 16) & 1u);   // RNE
  return (unsigned short)(u >> 16);
}

// One launch: zero xp border | weight->w3 granules | ori*mask->xp packed NHWC bf16
// w3 granule layout (unchanged from r6-r13):
// g = shift*128 + cic*32 + qm*16 + kk*8 + wm*2 + mi ; elem = g*512 + l*8 + e
// co = qm*128 + wm*32 + mi*16 + (l&15) ; ci = cic*64 + kk*32 + (l>>4)*8 + e
__global__ void prep_all(const float* __restrict__ ori, const int* __restrict__ mask,
                         const float* __restrict__ w,
                         unsigned short* __restrict__ xp, unsigned short* __restrict__ w3) {
  __shared__ float tile[64][65];
  const int bid = blockIdx.x;
  const int t = threadIdx.x;

  if (bid < NBORD) {
    int g = bid * 256 + t;
    int pos = g >> 5;
    int c = (g & 31) << 3;
    int n = pos / 644;
    int p = pos - n * 644;
    int y, x;
    if (p < 324) { y = (p < 162) ? 0 : 161; x = (p < 162) ? p : p - 162; }
    else { int q = p - 324; y = 1 + (q >> 1); x = (q & 1) ? 161 : 0; }
    unsigned short* d = xp + (((size_t)(n * 162 + y)) * 162 + x) * 256 + c;
    *(uint4*)d = (uint4){0u, 0u, 0u, 0u};
    return;
  }
  if (bid < NBORD + NPW) {
    int i = (bid - NBORD) * 256 + t;
    int e = i & 7, l = (i >> 3) & 63, g = i >> 9;
    int mi = g & 1, wm = (g >> 1) & 3, kk = (g >> 3) & 1;
    int qm = (g >> 4) & 1, cic = (g >> 5) & 3, shift = g >> 7;
    int co = qm * 128 + wm * 32 + mi * 16 + (l & 15);
    int ci = cic * 64 + kk * 32 + (l >> 4) * 8 + e;
    w3[i] = f2bf(w[(co * 256 + ci) * 9 + shift]);
    return;
  }

  // prep_x: bid2 = ((n*160+h)*4+cit)*3+wt
  int bid2 = bid - (NBORD + NPW);
  int wt = bid2 % 3;
  int t1 = bid2 / 3;
  int cit = t1 & 3;
  int t2 = t1 >> 2;
  int h = t2 % Hh;
  int n = t2 / Hh;

  int wl = t & 63;
  int ww = wt * 64 + wl;
  bool valid = (ww < Ww);
  float m = 0.f;
  if (valid) m = (float)mask[(n * Hh + h) * Ww + ww];
  const float* src = ori + (((size_t)(n * CI + cit * 64) * Hh + h) * Ww + ww);
  int r0 = t >> 6;
#pragma unroll
  for (int k = 0; k < 16; ++k) {
    int ci_l = r0 * 16 + k;
    float v = 0.f;
    if (valid) v = src[(size_t)ci_l * HWp] * m;
    tile[ci_l][wl] = v;
  }
  __syncthreads();

  int wl2 = t >> 2;
  int wo = wt * 64 + wl2;
  if (wo < Ww) {
    int cseg = (t & 3) * 16;
    union { unsigned short u[8]; uint4 v; } p0, p1;
#pragma unroll
    for (int j = 0; j < 8; ++j) p0.u[j] = f2bf(tile[cseg + j][wl2]);
#pragma unroll
    for (int j = 0; j < 8; ++j) p1.u[j] = f2bf(tile[cseg + 8 + j][wl2]);
    unsigned short* dst = xp + ((size_t)((n * HP + h + 1) * WP) + (wo + 1)) * CI + cit * 64 + cseg;
    *(uint4*)dst = p0.v;
    *(uint4*)(dst + 8) = p1.v;
  }
}

__device__ __forceinline__ void gload16(const unsigned short* g, unsigned short* l) {
  __builtin_amdgcn_global_load_lds((const __attribute__((address_space(1))) void*)g,
                                   (__attribute__((address_space(3))) void*)l, 16, 0, 0);
}

// Implicit GEMM, SINGLE 8-wave block per CU (one barrier domain; r12 ran 2x4-wave
// blocks at 288 regs/wave -> only 7 waves/CU resident, cross-block convoy, 46% util).
// Block 512 thr = 8 waves (4 co-quarters x 2 px-halves) = 256co x 160px (one image
// row). Wave 64co x 80px: acc[4][5] f32x4 (80) + aK0/aK1 (64) + bb[5] (40) ~= 215
// regs <= 256 -> true 8 waves/CU. LDS: B 3-slot 20KB ring (60KB); regs force 1
// block/CU -> grid 1280 = EXACTLY 5 rounds of 256 CUs, zero tail.
// Per tile 2 phases (kk half): {issue VMEM -> 5 ds_read -> s_barrier -> setprio(1)
// -> 20 MFMA -> setprio(0) -> s_barrier}. Stage: waves 0-3 issue 3 granules, 4-7
// issue 2 (160 rows = 20 x 8-row granules) -> per-wave counted end-of-tile wait
// vmcnt(11)/vmcnt(10) (drains stage(t+1), keeps stage(t+2)+A(t+1) in flight).
// A direct-to-reg halves refilled at hazard-free points (proven r11-r13 pattern).
__global__ void __launch_bounds__(512, 2)
sconv_gemm(const unsigned short* __restrict__ xp, const unsigned short* __restrict__ w3,
           const float* __restrict__ bias, float* __restrict__ out) {
  __shared__ unsigned short Bs[3][BSLOT];   // 60KB

  const int bid = blockIdx.x;
  const int n = bid & 7;            // image per XCD
  const int h = bid >> 3;           // output row

  const int t = threadIdx.x;
  const int l = t & 63;
  const int wv = t >> 6;            // 8 waves
  const int q = wv >> 1;            // co-quarter 0..3 (64 co)
  const int wn = wv & 1;            // px-half 0..1 (80 px)

  const int lr = l >> 3;
  const int swz8 = ((l & 7) ^ lr) << 3;   // proven source pre-swizzle (shorts)
  const int lc = l & 15, hi4 = l >> 4, lx7 = l & 7;
  const unsigned xrow = (unsigned)(n * HP + h);

  // stage granules: wave covers rows {wv*8, 64+wv*8, 128+wv*8 (wv<4)}
  const unsigned boff0 = (unsigned)(wv * 8 + lr) * 256 + swz8;

  f32x4 acc[4][5];
#pragma unroll
  for (int j = 0; j < 4; ++j)
#pragma unroll
    for (int ni = 0; ni < 5; ++ni)
      acc[j][ni] = (f32x4){0.f, 0.f, 0.f, 0.f};

  short8 aK0[4], aK1[4], bb[5];

#define TPAR(ts, cic, sh, kh, kw)                                             \
  const int cic = ((ts) * 57) >> 9;                                           \
  const int sh = (ts) - cic * 9;                                              \
  const int kh = (sh * 11) >> 5;                                              \
  const int kw = sh - kh * 3;

  auto STG = [&](int ts, unsigned short* slot) {
    TPAR(ts, cic, sh, kh, kw)
    (void)sh;
    const unsigned short* src = xp + ((size_t)(xrow + kh) * WP + kw) * 256 + (cic << 6) + boff0;
    unsigned short* dst = slot + (wv * 8) * 64;
    gload16(src, dst);
    gload16(src + 64 * 256, dst + 64 * 64);
    if (wv < 4) gload16(src + 128 * 256, dst + 128 * 64);
  };

  // A frags for co-quarter q, kk-half: granule = sh*128+cic*32+(q>>1)*16+kk*8+(q&1)*4+j
  auto AGH = [&](int ts, int kk, short8* dst) {
    TPAR(ts, cic, sh, kh, kw)
    (void)kh; (void)kw;
    const unsigned short* p = w3 +
        ((size_t)(sh * 128 + cic * 32 + (q >> 1) * 16 + kk * 8 + (q & 1) * 4) << 9) + (l << 3);
#pragma unroll
    for (int j = 0; j < 4; ++j)
      dst[j] = *(const short8*)(p + (j << 9));
  };

#define BBR(slot, kk) do {                                                    \
  _Pragma("unroll")                                                           \
  for (int i = 0; i < 5; ++i)                                                 \
    bb[i] = *(const short8*)((slot) + ((wn * 80 + i * 16 + lc) * 64) +        \
                             (((((kk) << 2) + hi4) ^ lx7) << 3));             \
} while (0)

#define CL(AH) do {                                                           \
  __builtin_amdgcn_s_setprio(1);                                              \
  _Pragma("unroll")                                                           \
  for (int j = 0; j < 4; ++j)                                                 \
    _Pragma("unroll")                                                         \
    for (int i = 0; i < 5; ++i)                                               \
      acc[j][i] = __builtin_amdgcn_mfma_f32_16x16x32_bf16(                    \
          AH[j], bb[i], acc[j][i], 0, 0, 0);                                  \
  __builtin_amdgcn_s_setprio(0);                                              \
} while (0)

  // phase: issues -> ds_reads -> barrier -> MFMA (compiler-counted lgkm) -> barrier
#define PH(slot, kk, AH, ISSUES, ENDW) do {                                   \
  ISSUES                                                                      \
  BBR(slot, kk);                                                              \
  __builtin_amdgcn_s_barrier();                                               \
  CL(AH);                                                                     \
  ENDW                                                                        \
  __builtin_amdgcn_s_barrier();                                               \
} while (0)

  // end-of-tile counted wait: per-wave-group (3 vs 2 stage issues), never 0
#define TILEWAIT do {                                                         \
  if (wv < 4) asm volatile("s_waitcnt vmcnt(11)" ::: "memory");               \
  else        asm volatile("s_waitcnt vmcnt(10)" ::: "memory");               \
} while (0)

#define TILE(tt, sc, sn) do {                                                 \
  PH(sc, 0, aK0, { STG((tt) + 2, sn); }, {});                                 \
  PH(sc, 1, aK1, { AGH((tt) + 1, 0, aK0); },                                  \
     { AGH((tt) + 1, 1, aK1); TILEWAIT; });                                   \
} while (0)

  unsigned short* const s0 = &Bs[0][0];
  unsigned short* const s1 = &Bs[1][0];
  unsigned short* const s2 = &Bs[2][0];

  // prologue: stage tiles 0,1; load A(0); single full drain (prologue only)
  STG(0, s0);
  STG(1, s1);
  AGH(0, 0, aK0);
  AGH(0, 1, aK1);
  asm volatile("s_waitcnt vmcnt(0)" ::: "memory");
  __builtin_amdgcn_s_barrier();

  // tiles 0..32 rolled; 33 staged-single; 34,35 peeled
  for (int t3 = 0; t3 < 33; t3 += 3) {
    TILE(t3 + 0, s0, s2);
    TILE(t3 + 1, s1, s0);
    TILE(t3 + 2, s2, s1);
  }
  TILE(33, s0, s2);
  // tile 34 (slot s1): A(35) halves at hazard-free points; drain stage(35)
  PH(s1, 0, aK0, {}, {});
  PH(s1, 1, aK1, { AGH(35, 0, aK0); },
     { AGH(35, 1, aK1);
       asm volatile("s_waitcnt vmcnt(8)" ::: "memory"); });
  // tile 35 (slot s2): final
  PH(s2, 0, aK0, {}, {});
  {
    BBR(s2, 1);
    CL(aK1);
  }

  // epilogue: D col(px)=l&15, row(co)=(l>>4)*4+r
#pragma unroll
  for (int j = 0; j < 4; ++j) {
    int cobase = q * 64 + j * 16 + hi4 * 4;
    const float4 bv = *(const float4*)(bias + cobase);
    float* op = out + (((size_t)n * CO + cobase) * Hh + h) * Ww;
#pragma unroll
    for (int ni = 0; ni < 5; ++ni) {
      int w = wn * 80 + ni * 16 + lc;
      f32x4 v = acc[j][ni];
      op[w]                   = v[0] + bv.x;
      op[(size_t)HWp + w]     = v[1] + bv.y;
      op[(size_t)2 * HWp + w] = v[2] + bv.z;
      op[(size_t)3 * HWp + w] = v[3] + bv.w;
    }
  }
}

extern "C" void kernel_launch(void* const* d_in, const int* in_sizes, int n_in,
                              void* d_out, int out_size, void* d_ws, size_t ws_size,
                              hipStream_t stream) {
  const int* mask = (const int*)d_in[0];
  const float* ori = (const float*)d_in[1];
  const float* weight = (const float*)d_in[2];
  const float* bias = (const float*)d_in[3];
  float* out = (float*)d_out;

  unsigned short* xp = (unsigned short*)d_ws;          // padded NHWC bf16, 107.5 MB
  unsigned short* w3 = xp + XPAD_ELEMS;                // 1.2 MB granule-ordered weights

  prep_all<<<NBORD + NPW + NPX, 256, 0, stream>>>(ori, mask, weight, xp, w3);
  sconv_gemm<<<1280, 512, 0, stream>>>(xp, w3, bias, out);
}

// Round 15
// 339.193 us; speedup vs baseline: 1.0858x; 1.0858x over previous
//
#include <hip/hip_runtime.h>

typedef __attribute__((ext_vector_type(8))) short short8;
typedef __attribute__((ext_vector_type(4))) float f32x4;

#define B_    8
#define CI    256
#define CO    256
#define Hh    160
#define Ww    160
#define HP    162
#define WP    162
#define HWp   (Hh * Ww)                 // 25600
#define XPAD_ELEMS (B_ * HP * WP * CI)  // 53,747,712 bf16
#define W3_ELEMS   (9 * CI * CO)        // 589,824 bf16 (granule order)
#define NT    36                        // 4 ci-chunks x 9 shifts, BK=64
#define BSLOT (128 * 64)                // shorts per B slot: 128px x 64ci = 16KB

// fused prep grid partition
#define NBORD 644
#define NPW   2304                      // 589824 / 256
#define NPX   (B_ * Hh * 4 * 3)        // 15360

__device__ __forceinline__ unsigned short f2bf(float f) {
  unsigned int u = __float_as_uint(f);
  u += 0x7FFFu + ((u >> 16) & 1u);   // RNE
  return (unsigned short)(u >> 16);
}

// One launch: zero xp border | weight->w3 granules | ori*mask->xp packed NHWC bf16
// w3 granule layout (unchanged from r6-r14):
// g = shift*128 + cic*32 + qm*16 + kk*8 + wm*2 + mi ; elem = g*512 + l*8 + e
// co = qm*128 + wm*32 + mi*16 + (l&15) ; ci = cic*64 + kk*32 + (l>>4)*8 + e
__global__ void prep_all(const float* __restrict__ ori, const int* __restrict__ mask,
                         const float* __restrict__ w,
                         unsigned short* __restrict__ xp, unsigned short* __restrict__ w3) {
  __shared__ float tile[64][65];
  const int bid = blockIdx.x;
  const int t = threadIdx.x;

  if (bid < NBORD) {
    int g = bid * 256 + t;
    int pos = g >> 5;
    int c = (g & 31) << 3;
    int n = pos / 644;
    int p = pos - n * 644;
    int y, x;
    if (p < 324) { y = (p < 162) ? 0 : 161; x = (p < 162) ? p : p - 162; }
    else { int q = p - 324; y = 1 + (q >> 1); x = (q & 1) ? 161 : 0; }
    unsigned short* d = xp + (((size_t)(n * 162 + y)) * 162 + x) * 256 + c;
    *(uint4*)d = (uint4){0u, 0u, 0u, 0u};
    return;
  }
  if (bid < NBORD + NPW) {
    int i = (bid - NBORD) * 256 + t;
    int e = i & 7, l = (i >> 3) & 63, g = i >> 9;
    int mi = g & 1, wm = (g >> 1) & 3, kk = (g >> 3) & 1;
    int qm = (g >> 4) & 1, cic = (g >> 5) & 3, shift = g >> 7;
    int co = qm * 128 + wm * 32 + mi * 16 + (l & 15);
    int ci = cic * 64 + kk * 32 + (l >> 4) * 8 + e;
    w3[i] = f2bf(w[(co * 256 + ci) * 9 + shift]);
    return;
  }

  // prep_x: bid2 = ((n*160+h)*4+cit)*3+wt
  int bid2 = bid - (NBORD + NPW);
  int wt = bid2 % 3;
  int t1 = bid2 / 3;
  int cit = t1 & 3;
  int t2 = t1 >> 2;
  int h = t2 % Hh;
  int n = t2 / Hh;

  int wl = t & 63;
  int ww = wt * 64 + wl;
  bool valid = (ww < Ww);
  float m = 0.f;
  if (valid) m = (float)mask[(n * Hh + h) * Ww + ww];
  const float* src = ori + (((size_t)(n * CI + cit * 64) * Hh + h) * Ww + ww);
  int r0 = t >> 6;
#pragma unroll
  for (int k = 0; k < 16; ++k) {
    int ci_l = r0 * 16 + k;
    float v = 0.f;
    if (valid) v = src[(size_t)ci_l * HWp] * m;
    tile[ci_l][wl] = v;
  }
  __syncthreads();

  int wl2 = t >> 2;
  int wo = wt * 64 + wl2;
  if (wo < Ww) {
    int cseg = (t & 3) * 16;
    union { unsigned short u[8]; uint4 v; } p0, p1;
#pragma unroll
    for (int j = 0; j < 8; ++j) p0.u[j] = f2bf(tile[cseg + j][wl2]);
#pragma unroll
    for (int j = 0; j < 8; ++j) p1.u[j] = f2bf(tile[cseg + 8 + j][wl2]);
    unsigned short* dst = xp + ((size_t)((n * HP + h + 1) * WP) + (wo + 1)) * CI + cit * 64 + cseg;
    *(uint4*)dst = p0.v;
    *(uint4*)(dst + 8) = p1.v;
  }
}

__device__ __forceinline__ void gload16(const unsigned short* g, unsigned short* l) {
  __builtin_amdgcn_global_load_lds((const __attribute__((address_space(1))) void*)g,
                                   (__attribute__((address_space(3))) void*)l, 16, 0, 0);
}

// Implicit GEMM tuned for 3 blocks/CU (12 waves, 3/SIMD TLP — the mechanism every
// prior config lacked: all plateaued at 46% with 2/SIMD barrier-locked waves).
// Block 128co x 128px, 256 thr = 4 waves (2m x 2n); wave 64co x 64px:
// acc[4][4] f32x4 = 64 AGPR + aK0/aK1 32 + bb 16 + addr ~40 => ~160 regs/wave
// (fits launch_bounds(256,3)'s 170 cap; r7's spill was at 285).
// LDS: B 3-slot 16KB ring = 48KB -> 3 blocks/CU = 144KB. Three desynced barrier
// domains/CU; per SIMD 3 waves overlap ds/MFMA/stage windows.
// Per tile 2 phases (kk): {issue VMEM -> 4 ds_read -> s_barrier -> setprio(1) ->
// 16 MFMA -> setprio(0) -> s_barrier}; counted vmcnt(12)/tile (never 0 mid-loop).
// A direct-to-reg halves at hazard-free points (r11-r13 proven). Grid 3200 =
// 8 img (XCD-owned) x 2 co-half (adjacent: B L2-hot) x 200 px-tiles.
__global__ void __launch_bounds__(256, 3)
sconv_gemm(const unsigned short* __restrict__ xp, const unsigned short* __restrict__ w3,
           const float* __restrict__ bias, float* __restrict__ out) {
  __shared__ unsigned short Bs[3][BSLOT];   // 48KB

  const int bid = blockIdx.x;
  const int n = bid & 7;            // image per XCD
  const int rest = bid >> 3;        // 0..399
  const int ch = rest & 1;          // co half (pairs share px-tile -> B L2-hot)
  const int pxt = rest >> 1;        // 0..199
  const int p0 = pxt * 128;         // first pixel within image

  const int t = threadIdx.x;
  const int l = t & 63;
  const int wv = t >> 6;            // 4 waves
  const int wm = wv >> 1;           // 0..1: co 64-half of the 128
  const int wn = wv & 1;            // 0..1: px 64-half of the 128

  const int lr = l >> 3;
  const int swz8 = ((l & 7) ^ lr) << 3;   // proven source pre-swizzle (shorts)
  const int lc = l & 15, hi4 = l >> 4, lx7 = l & 7;

  // B staging: wave wv covers px rows [wv*32, wv*32+32), 4 granules of 8 rows
  unsigned boff[4];
#pragma unroll
  for (int g = 0; g < 4; ++g) {
    int p = p0 + wv * 32 + g * 8 + lr;
    int h = p / Ww;
    int w = p - h * Ww;
    boff[g] = (unsigned)((n * HP + h) * WP + w) * 256 + swz8;
  }

  f32x4 acc[4][4];
#pragma unroll
  for (int j = 0; j < 4; ++j)
#pragma unroll
    for (int i = 0; i < 4; ++i)
      acc[j][i] = (f32x4){0.f, 0.f, 0.f, 0.f};

  short8 aK0[4], aK1[4], bb[4];

#define TPAR(ts, cic, sh, kh, kw)                                             \
  const int cic = ((ts) * 57) >> 9;                                           \
  const int sh = (ts) - cic * 9;                                              \
  const int kh = (sh * 11) >> 5;                                              \
  const int kw = sh - kh * 3;

  auto STG = [&](int ts, unsigned short* slot) {
    TPAR(ts, cic, sh, kh, kw)
    (void)sh;
    const unsigned bd = (unsigned)(kh * WP + kw) * 256 + (cic << 6);
    unsigned short* dst = slot + wv * 2048;
#pragma unroll
    for (int g = 0; g < 4; ++g)
      gload16(xp + bd + boff[g], dst + g * 512);
  };

  // A frags for (ch, wm) 64 co, kk-half: granules sh*128+cic*32+ch*16+kk*8+wm*4+j
  auto AGH = [&](int ts, int kk, short8* dst) {
    TPAR(ts, cic, sh, kh, kw)
    (void)kh; (void)kw;
    const unsigned short* p = w3 +
        ((size_t)(sh * 128 + cic * 32 + ch * 16 + kk * 8 + wm * 4) << 9) + (l << 3);
#pragma unroll
    for (int j = 0; j < 4; ++j)
      dst[j] = *(const short8*)(p + (j << 9));
  };

#define BBR(slot, kk) do {                                                    \
  _Pragma("unroll")                                                           \
  for (int i = 0; i < 4; ++i)                                                 \
    bb[i] = *(const short8*)((slot) + ((wn * 64 + i * 16 + lc) * 64) +        \
                             (((((kk) << 2) + hi4) ^ lx7) << 3));             \
} while (0)

#define CL(AH) do {                                                           \
  __builtin_amdgcn_s_setprio(1);                                              \
  _Pragma("unroll")                                                           \
  for (int j = 0; j < 4; ++j)                                                 \
    _Pragma("unroll")                                                         \
    for (int i = 0; i < 4; ++i)                                               \
      acc[j][i] = __builtin_amdgcn_mfma_f32_16x16x32_bf16(                    \
          AH[j], bb[i], acc[j][i], 0, 0, 0);                                  \
  __builtin_amdgcn_s_setprio(0);                                              \
} while (0)

  // phase: issues -> ds_reads -> barrier -> MFMA (compiler-counted lgkm) -> barrier
#define PH(slot, kk, AH, ISSUES, ENDW) do {                                   \
  ISSUES                                                                      \
  BBR(slot, kk);                                                              \
  __builtin_amdgcn_s_barrier();                                               \
  CL(AH);                                                                     \
  ENDW                                                                        \
  __builtin_amdgcn_s_barrier();                                               \
} while (0)

#define TILE(tt, sc, sn) do {                                                 \
  PH(sc, 0, aK0, { STG((tt) + 2, sn); }, {});                                 \
  PH(sc, 1, aK1, { AGH((tt) + 1, 0, aK0); },                                  \
     { AGH((tt) + 1, 1, aK1);                                                 \
       asm volatile("s_waitcnt vmcnt(12)" ::: "memory"); });                  \
} while (0)

  unsigned short* const s0 = &Bs[0][0];
  unsigned short* const s1 = &Bs[1][0];
  unsigned short* const s2 = &Bs[2][0];

  // prologue: stage tiles 0,1; load A(0); vmcnt(12) drains STG(0) only
  STG(0, s0);
  STG(1, s1);
  AGH(0, 0, aK0);
  AGH(0, 1, aK1);
  asm volatile("s_waitcnt vmcnt(12)" ::: "memory");
  __builtin_amdgcn_s_barrier();

  // tiles 0..32 rolled; 33 staged-single; 34,35 peeled
  for (int t3 = 0; t3 < 33; t3 += 3) {
    TILE(t3 + 0, s0, s2);
    TILE(t3 + 1, s1, s0);
    TILE(t3 + 2, s2, s1);
  }
  TILE(33, s0, s2);
  // tile 34 (slot s1): A(35) halves at hazard-free points; ensure STG(35) landed
  PH(s1, 0, aK0, {}, {});
  PH(s1, 1, aK1, { AGH(35, 0, aK0); },
     { AGH(35, 1, aK1);
       asm volatile("s_waitcnt vmcnt(8)" ::: "memory"); });
  // tile 35 (slot s2): final
  PH(s2, 0, aK0, {}, {});
  {
    BBR(s2, 1);
    CL(aK1);
  }

  // epilogue: D col(px)=l&15, row(co)=(l>>4)*4+r
#pragma unroll
  for (int j = 0; j < 4; ++j) {
    int cobase = ch * 128 + wm * 64 + j * 16 + hi4 * 4;
    const float4 bv = *(const float4*)(bias + cobase);
#pragma unroll
    for (int i = 0; i < 4; ++i) {
      int px = p0 + wn * 64 + i * 16 + lc;
      float* op = out + ((size_t)n * CO + cobase) * HWp + px;
      f32x4 v = acc[j][i];
      op[0]               = v[0] + bv.x;
      op[(size_t)HWp]     = v[1] + bv.y;
      op[(size_t)2 * HWp] = v[2] + bv.z;
      op[(size_t)3 * HWp] = v[3] + bv.w;
    }
  }
}

extern "C" void kernel_launch(void* const* d_in, const int* in_sizes, int n_in,
                              void* d_out, int out_size, void* d_ws, size_t ws_size,
                              hipStream_t stream) {
  const int* mask = (const int*)d_in[0];
  const float* ori = (const float*)d_in[1];
  const float* weight = (const float*)d_in[2];
  const float* bias = (const float*)d_in[3];
  float* out = (float*)d_out;

  unsigned short* xp = (unsigned short*)d_ws;          // padded NHWC bf16, 107.5 MB
  unsigned short* w3 = xp + XPAD_ELEMS;                // 1.2 MB granule-ordered weights

  prep_all<<<NBORD + NPW + NPX, 256, 0, stream>>>(ori, mask, weight, xp, w3);
  sconv_gemm<<<3200, 256, 0, stream>>>(xp, w3, bias, out);
}